// Round 11
// baseline (14629.388 us; speedup 1.0000x reference)
//
#include <hip/hip_runtime.h>
#include <math.h>

// ===== problem constants (washout hardcoded=200 per reference) =====
#define NH      2048
#define TT      4096
#define DIN     64
#define WASH    200
#define TW      (TT - WASH)      // 3896
#define LAMBDA  1e-6f

#define CG_BLOCKS    64
#define CG_ITERS     256
#define NTILE        528         // 32*33/2 upper-tri 64x64 tiles
#define NWORK        192         // gram worker blocks (64..255)

typedef unsigned long long u64;

// ===== workspace layout =====
// floats:
#define X_OFF      ((size_t)0)                 // TT*NH (32 MB)
#define DRIVE_OFF  ((size_t)TT * NH)           // TT*NH (dead after scan)
#define A_OFF      DRIVE_OFF                   // NH*NH aliases drive rows<2048
#define B_OFF      ((size_t)2 * TT * NH)       // NH
#define WS_FLOATS  (B_OFF + NH)                // even -> u64 area 8B-aligned
// u64s (at ws + WS_FLOATS):
#define XPACK_OFF  ((size_t)0)                 // 2*NH (double-buffered packed x)
#define ZPACK_OFF  ((size_t)2 * NH)            // NH   (packed z / final x for CG)
#define PQSLOT_OFF ((size_t)3 * NH)            // 64   ((p,q) partials)
#define RZSLOT_OFF ((size_t)3 * NH + 64)       // 64   ((r,z) partials)
#define U64_TOTAL  ((size_t)3 * NH + 128)

__device__ __forceinline__ u64 pack_ev(int epoch, float v) {
    return ((u64)(unsigned)epoch << 32) | (u64)__float_as_uint(v);
}
__device__ __forceinline__ int   ep_of(u64 p)  { return (int)(p >> 32); }
__device__ __forceinline__ float val_of(u64 p) { return __uint_as_float((unsigned)p); }
__device__ __forceinline__ u64 pack2f(float lo, float hi) {
    return ((u64)__float_as_uint(hi) << 32) | (u64)__float_as_uint(lo);
}
__device__ __forceinline__ float lo_of(u64 p) { return __uint_as_float((unsigned)p); }
__device__ __forceinline__ float hi_of(u64 p) { return __uint_as_float((unsigned)(p >> 32)); }

__device__ __forceinline__ u64 aload(const u64* p) {
    return __hip_atomic_load(p, __ATOMIC_RELAXED, __HIP_MEMORY_SCOPE_AGENT);
}
__device__ __forceinline__ void astore(u64* p, u64 v) {
    __hip_atomic_store(p, v, __ATOMIC_RELAXED, __HIP_MEMORY_SCOPE_AGENT);
}

// ===== init =====
__global__ void init_kernel(float* ws) {
    int tid = threadIdx.x;
    u64* ub = (u64*)(ws + WS_FLOATS);
    for (size_t i = tid; i < U64_TOTAL; i += 256) ub[i] = 0ull;
}

// ===== drive = u @ W_in.T =====
__global__ __launch_bounds__(256) void drive_kernel(
    const float* __restrict__ u, const float* __restrict__ Win,
    float* __restrict__ drive)
{
    __shared__ float Wt[256 * 64];
    const int tid = threadIdx.x;
    const int ic = blockIdx.x & 7;
    const int tc = blockIdx.x >> 3;
    const int i0 = ic * 256;
    for (int idx = tid; idx < 256 * 64; idx += 256) {
        int il = idx >> 6, k = idx & 63;
        Wt[k * 256 + il] = Win[(size_t)i0 * 64 + idx];
    }
    __syncthreads();
    for (int tt_ = 0; tt_ < 128; ++tt_) {
        int t = tc * 128 + tt_;
        const float* ur = u + (size_t)t * DIN;
        float acc = 0.f;
        #pragma unroll
        for (int k = 0; k < 64; ++k)
            acc = fmaf(Wt[k * 256 + tid], ur[k], acc);
        drive[(size_t)t * NH + i0 + tid] = acc;
    }
}

// ===== fused scan + gram + bvec: 256 blocks x 1024 threads =====
// Scan (blocks 0..63): R8-proven sync protocol; xls double-buffered so the
// trailing barrier is dropped (step t+2's writes to buffer t&1 occur only
// after step t+1's phase-A barrier, which no wave passes before all waves
// finished reading buffer t&1). bvec accumulated in the sync shadow by
// lane 0 (2 FMAs/step) and written at the end.
// Workers (64..255): R8 verbatim.
__global__ __launch_bounds__(1024, 1) void scan_gram_kernel(
    const float* __restrict__ W, const float* __restrict__ drive,
    const float* __restrict__ y,
    float* __restrict__ X, u64* xpack, float* __restrict__ A,
    float* __restrict__ bv)
{
    __shared__ float xls[2][NH];       // 16 KB (scan, double-buffered)
    __shared__ float As[16][64];       // 4 KB (worker)
    __shared__ float Bs[16][64];       // 4 KB (worker)
    const int tid = threadIdx.x;

    if (blockIdx.x < 64) {
        // ================= scan path =====================================
        const int wave = tid >> 6;       // 16 waves
        const int lane = tid & 63;
        const int rowA = blockIdx.x * 32 + wave * 2;

        float4 wA[8], wB[8];
        {
            const float* wpA = W + (size_t)rowA * NH + lane * 4;
            const float* wpB = wpA + NH;
            #pragma unroll
            for (int j = 0; j < 8; ++j) {
                wA[j] = *(const float4*)(wpA + 256 * j);
                wB[j] = *(const float4*)(wpB + 256 * j);
            }
        }

        float b0 = 0.f, b1 = 0.f;        // bvec accumulators (lane 0)

        for (int t = 0; t < TT; ++t) {
            float* xb = xls[t & 1];
            float2 dv = {0.f, 0.f};
            if (lane == 0) dv = *(const float2*)&drive[(size_t)t * NH + rowA];

            if (t == 0) {
                xb[tid] = 0.f; xb[tid + 1024] = 0.f;
            } else {
                const u64* src = xpack + (size_t)((t - 1) & 1) * NH;
                const int want = t;
                u64 a = aload(&src[tid]);
                u64 b = aload(&src[tid + 1024]);
                bool pa = true, pb = true;
                if (ep_of(a) >= want) { xb[tid] = val_of(a); pa = false; }
                if (ep_of(b) >= want) { xb[tid + 1024] = val_of(b); pb = false; }
                while (pa || pb) {
                    __builtin_amdgcn_s_sleep(1);
                    if (pa) { u64 v = aload(&src[tid]);
                              if (ep_of(v) >= want) { xb[tid] = val_of(v); pa = false; } }
                    if (pb) { u64 v = aload(&src[tid + 1024]);
                              if (ep_of(v) >= want) { xb[tid + 1024] = val_of(v); pb = false; } }
                }
            }
            __syncthreads();   // phase-A barrier (write -> read, same buffer)

            float a0 = 0.f, a1 = 0.f;
            #pragma unroll
            for (int j = 0; j < 8; ++j) {
                float4 xv = *(const float4*)&xb[lane * 4 + 256 * j];
                float4 va = wA[j], vb = wB[j];
                a0 = fmaf(va.x, xv.x, fmaf(va.y, xv.y, fmaf(va.z, xv.z, fmaf(va.w, xv.w, a0))));
                a1 = fmaf(vb.x, xv.x, fmaf(vb.y, xv.y, fmaf(vb.z, xv.z, fmaf(vb.w, xv.w, a1))));
            }
            #pragma unroll
            for (int m = 32; m; m >>= 1) { a0 += __shfl_xor(a0, m); a1 += __shfl_xor(a1, m); }

            if (lane == 0) {
                float v0 = tanhf(a0 + dv.x);
                float v1 = tanhf(a1 + dv.y);
                astore((u64*)&X[(size_t)t * NH + rowA], pack2f(v0, v1));
                u64* dst = xpack + (size_t)(t & 1) * NH;
                astore(&dst[rowA],     pack_ev(t + 1, v0));
                astore(&dst[rowA + 1], pack_ev(t + 1, v1));
                if (t >= WASH) {
                    float yv = y[t];
                    b0 = fmaf(v0, yv, b0);
                    b1 = fmaf(v1, yv, b1);
                }
            }
            // no trailing barrier (double-buffered xls)
        }
        // final: make X[TT-1] provably visible, then sentinel epoch
        __threadfence();
        if (lane == 0) {
            u64* dst = xpack + (size_t)(TT & 1) * NH;   // buffer 0
            astore(&dst[rowA],     pack_ev(TT + 1, 0.f));
            astore(&dst[rowA + 1], pack_ev(TT + 1, 0.f));
            bv[rowA]     = b0;       // read by cg_kernel (stream-ordered)
            bv[rowA + 1] = b1;
        }
    } else {
        // ================= gram worker path (R8 verbatim) ==================
        const int wid = blockIdx.x - 64;         // 0..191
        int ti0[3], tj0[3]; int nt = 0;
        for (int L = wid; L < NTILE; L += NWORK) {
            int rem = L, a = 0;
            while (rem >= 32 - a) { rem -= 32 - a; ++a; }
            ti0[nt] = a * 64; tj0[nt] = (a + rem) * 64; ++nt;
        }
        float4 acc4[3] = {};
        const int ty = tid >> 5, tx = tid & 31;
        const u64* Xp = (const u64*)X;

        const int nch = (TW + 15) / 16;          // 244
        for (int ch = 0; ch < nch; ++ch) {
            const int tb = WASH + ch * 16;
            const int te = (tb + 15 < TT) ? tb + 15 : TT - 1;
            const int want = te + 2;
            const u64* buf = xpack + (size_t)((te + 1) & 1) * NH;
            if (tid < nt * 128) {
                int tt_ = tid >> 7, local = tid & 127;
                int base = (local & 64) ? tj0[tt_] : ti0[tt_];
                int r = base + (local & 63);
                u64 v = aload(&buf[r]);
                while (ep_of(v) < want) { __builtin_amdgcn_s_sleep(64); v = aload(&buf[r]); }
            }
            __syncthreads();

            for (int tt_ = 0; tt_ < nt; ++tt_) {
                const int i0 = ti0[tt_], j0 = tj0[tt_];
                {   // stage 16x64 A-cols and B-cols (u64 = 2 floats per thread)
                    int v = tid & 511;
                    int kk = v >> 5, c2 = v & 31;
                    int t = tb + kk;
                    int base = (tid < 512) ? i0 : j0;
                    float lo = 0.f, hi = 0.f;
                    if (t < TT) {
                        u64 w_ = aload(&Xp[((size_t)t * NH + base) / 2 + c2]);
                        lo = lo_of(w_); hi = hi_of(w_);
                    }
                    float* Sh = (tid < 512) ? &As[kk][c2 * 2] : &Bs[kk][c2 * 2];
                    Sh[0] = lo; Sh[1] = hi;
                }
                __syncthreads();
                float4 a = acc4[tt_];
                #pragma unroll
                for (int k = 0; k < 16; ++k) {
                    float2 av = *(const float2*)&As[k][ty * 2];
                    float2 bv2 = *(const float2*)&Bs[k][tx * 2];
                    a.x = fmaf(av.x, bv2.x, a.x); a.y = fmaf(av.x, bv2.y, a.y);
                    a.z = fmaf(av.y, bv2.x, a.z); a.w = fmaf(av.y, bv2.y, a.w);
                }
                acc4[tt_] = a;
                __syncthreads();
            }
        }
        // writeout (scan fully done: last chunk required the sentinels)
        for (int tt_ = 0; tt_ < nt; ++tt_) {
            const int i0 = ti0[tt_], j0 = tj0[tt_];
            const bool diag = (i0 == j0);
            float4 a = acc4[tt_];
            float vals[2][2] = {{a.x, a.y}, {a.z, a.w}};
            #pragma unroll
            for (int aa = 0; aa < 2; ++aa) {
                int gi = i0 + ty * 2 + aa;
                #pragma unroll
                for (int bb = 0; bb < 2; ++bb) {
                    int gj = j0 + tx * 2 + bb;
                    float v = vals[aa][bb];
                    if (gi == gj) v += LAMBDA;
                    A[(size_t)gi * NH + gj] = v;
                    if (!diag) A[(size_t)gj * NH + gi] = v;
                }
            }
        }
    }
}

// ===== truth-based Jacobi-PCG (R10 verbatim, proven) + out epilogue =====
__global__ __launch_bounds__(1024, 1) void cg_kernel(
    const float* __restrict__ A, const float* __restrict__ bvec,
    const float* __restrict__ X, float* __restrict__ out,
    u64* zpack, u64* pqslot, u64* rzslot)
{
    __shared__ float pls[NH];        // persistent p (8 KB)
    __shared__ float zls[NH];        // gathered z / final Wout (8 KB)
    __shared__ float r32[32], x32[32], q32[32], inv32[32];
    __shared__ float csh[2];
    const int tid     = threadIdx.x;
    const int r_local = tid >> 5;
    const int lane32  = tid & 31;
    const int row0 = blockIdx.x * 32;
    const int row  = row0 + r_local;

    float4 areg[16];                 // A[row][lane32*4 + 128j ..] resident
    {
        const float* ap = A + (size_t)row * NH + lane32 * 4;
        #pragma unroll
        for (int j = 0; j < 16; ++j) areg[j] = *(const float4*)(ap + 128 * j);
    }

    pls[tid] = 0.f; pls[tid + 1024] = 0.f;

    if (tid < 32) {
        int i = row0 + tid;
        float bi = bvec[i];
        float iv = 1.0f / A[(size_t)i * NH + i];   // invdiag folded in
        inv32[tid] = iv;
        x32[tid] = 0.f; r32[tid] = bi;
        float zi = iv * bi;
        astore(&zpack[i], pack_ev(1, zi));
        float part = bi * zi;
        #pragma unroll
        for (int m = 16; m; m >>= 1) part += __shfl_xor(part, m, 32);
        if (tid == 0) astore(&rzslot[blockIdx.x], pack_ev(1, part));
    }
    __syncthreads();

    float rho_prev = 1.f;

    for (int it = 0; it < CG_ITERS; ++it) {
        // --- phase 1: gather z (epoch it+1) + rz slots -> rho, beta ---
        {
            const int want = it + 1;
            u64 a = aload(&zpack[tid]);
            u64 b = aload(&zpack[tid + 1024]);
            bool pa = true, pb = true;
            if (ep_of(a) >= want) { zls[tid] = val_of(a); pa = false; }
            if (ep_of(b) >= want) { zls[tid + 1024] = val_of(b); pb = false; }
            while (pa || pb) {
                __builtin_amdgcn_s_sleep(1);
                if (pa) { u64 v = aload(&zpack[tid]);
                          if (ep_of(v) >= want) { zls[tid] = val_of(v); pa = false; } }
                if (pb) { u64 v = aload(&zpack[tid + 1024]);
                          if (ep_of(v) >= want) { zls[tid + 1024] = val_of(v); pb = false; } }
            }
        }
        if (tid < 64) {
            u64 v = aload(&rzslot[tid]);
            while (ep_of(v) < it + 1) { __builtin_amdgcn_s_sleep(1); v = aload(&rzslot[tid]); }
            float s = val_of(v);
            #pragma unroll
            for (int m = 32; m; m >>= 1) s += __shfl_xor(s, m);
            if (tid == 0) csh[1] = s;
        }
        __syncthreads();
        float rho = csh[1];
        float beta = (it == 0) ? 0.f : ((rho_prev != 0.f) ? rho / rho_prev : 0.f);

        pls[tid]        = fmaf(beta, pls[tid],        zls[tid]);
        pls[tid + 1024] = fmaf(beta, pls[tid + 1024], zls[tid + 1024]);
        __syncthreads();

        float acc = 0.f;
        #pragma unroll
        for (int j = 0; j < 16; ++j) {
            float4 pv = *(const float4*)&pls[lane32 * 4 + 128 * j];
            float4 av = areg[j];
            acc = fmaf(av.x, pv.x, fmaf(av.y, pv.y,
                  fmaf(av.z, pv.z, fmaf(av.w, pv.w, acc))));
        }
        #pragma unroll
        for (int m = 16; m; m >>= 1) acc += __shfl_xor(acc, m, 32);
        if (lane32 == 0) q32[r_local] = acc;
        __syncthreads();

        if (tid < 32) {
            float t1 = q32[tid] * pls[row0 + tid];
            #pragma unroll
            for (int m = 16; m; m >>= 1) t1 += __shfl_xor(t1, m, 32);
            if (tid == 0) astore(&pqslot[blockIdx.x], pack_ev(it + 1, t1));
        }
        if (tid < 64) {
            u64 v = aload(&pqslot[tid]);
            while (ep_of(v) < it + 1) { __builtin_amdgcn_s_sleep(1); v = aload(&pqslot[tid]); }
            float s = val_of(v);
            #pragma unroll
            for (int m = 32; m; m >>= 1) s += __shfl_xor(s, m);
            if (tid == 0) csh[0] = s;
        }
        __syncthreads();
        float pq = csh[0];
        float alpha = (pq != 0.f) ? rho / pq : 0.f;

        if (tid < 32) {
            int i = row0 + tid;
            float pi = pls[i], qi = q32[tid];
            x32[tid] = fmaf(alpha, pi, x32[tid]);
            float ri = r32[tid] - alpha * qi;
            r32[tid] = ri;
            float zi = inv32[tid] * ri;
            astore(&zpack[i], pack_ev(it + 2, zi));
            float t2 = ri * zi;
            #pragma unroll
            for (int m = 16; m; m >>= 1) t2 += __shfl_xor(t2, m, 32);
            if (tid == 0) astore(&rzslot[blockIdx.x], pack_ev(it + 2, t2));
        }
        rho_prev = rho;
        __syncthreads();
    }

    // ===== out epilogue: publish final x (epoch CG_ITERS+2), gather, project =====
    if (tid < 32) {
        int i = row0 + tid;
        astore(&zpack[i], pack_ev(CG_ITERS + 2, x32[tid]));
    }
    {
        const int want = CG_ITERS + 2;
        u64 a = aload(&zpack[tid]);
        u64 b = aload(&zpack[tid + 1024]);
        bool pa = true, pb = true;
        if (ep_of(a) >= want) { zls[tid] = val_of(a); pa = false; }
        if (ep_of(b) >= want) { zls[tid + 1024] = val_of(b); pb = false; }
        while (pa || pb) {
            __builtin_amdgcn_s_sleep(1);
            if (pa) { u64 v = aload(&zpack[tid]);
                      if (ep_of(v) >= want) { zls[tid] = val_of(v); pa = false; } }
            if (pb) { u64 v = aload(&zpack[tid + 1024]);
                      if (ep_of(v) >= want) { zls[tid + 1024] = val_of(v); pb = false; } }
        }
    }
    __syncthreads();
    {
        const int i0r = (TW * (int)blockIdx.x) >> 6;       // TW*b/64
        const int i1r = (TW * ((int)blockIdx.x + 1)) >> 6;
        const int wave = tid >> 6, lane = tid & 63;
        for (int i = i0r + wave; i < i1r; i += 16) {
            const float* xr = X + (size_t)(WASH + i) * NH;
            float acc = 0.f;
            #pragma unroll
            for (int j = 0; j < 32; ++j)
                acc = fmaf(xr[j * 64 + lane], zls[j * 64 + lane], acc);
            #pragma unroll
            for (int m = 32; m; m >>= 1) acc += __shfl_xor(acc, m);
            if (lane == 0) out[i] = acc;
        }
    }
}

extern "C" void kernel_launch(void* const* d_in, const int* in_sizes, int n_in,
                              void* d_out, int out_size, void* d_ws, size_t ws_size,
                              hipStream_t stream)
{
    const float* u    = (const float*)d_in[0];   // (4096, 64)
    const float* y    = (const float*)d_in[1];   // (4096, 1)
    const float* Win  = (const float*)d_in[2];   // (2048, 64)
    const float* Wres = (const float*)d_in[3];   // (2048, 2048)
    // d_in[4] = washout (==200), hardcoded as WASH

    float* ws = (float*)d_ws;
    float* X     = ws + X_OFF;
    float* drive = ws + DRIVE_OFF;
    float* A     = ws + A_OFF;
    u64*   ub    = (u64*)(ws + WS_FLOATS);
    u64*   xpack  = ub + XPACK_OFF;
    u64*   zpack  = ub + ZPACK_OFF;
    u64*   pqslot = ub + PQSLOT_OFF;
    u64*   rzslot = ub + RZSLOT_OFF;

    init_kernel<<<1, 256, 0, stream>>>(ws);
    drive_kernel<<<256, 256, 0, stream>>>(u, Win, drive);
    scan_gram_kernel<<<256, 1024, 0, stream>>>(Wres, drive, y, X, xpack, A,
                                               ws + B_OFF);
    cg_kernel<<<CG_BLOCKS, 1024, 0, stream>>>(A, ws + B_OFF, X, (float*)d_out,
                                              zpack, pqslot, rzslot);
}

// Round 12
// 12078.535 us; speedup vs baseline: 1.2112x; 1.2112x over previous
//
#include <hip/hip_runtime.h>
#include <math.h>

// ===== problem constants (washout hardcoded=200 per reference) =====
#define NH      2048
#define TT      4096
#define DIN     64
#define WASH    200
#define TW      (TT - WASH)      // 3896
#define LAMBDA  1e-6f

#define CG_BLOCKS    64
#define CG_ITERS     256
#define NTILE        528         // 32*33/2 upper-tri 64x64 tiles
#define NWORK        192         // gram worker blocks (64..255)

typedef unsigned long long u64;

// ===== workspace layout =====
// floats:
#define X_OFF      ((size_t)0)                 // TT*NH (32 MB)
#define DRIVE_OFF  ((size_t)TT * NH)           // TT*NH (dead after scan)
#define A_OFF      DRIVE_OFF                   // NH*NH aliases drive rows<2048
#define B_OFF      ((size_t)2 * TT * NH)       // NH
#define WS_FLOATS  (B_OFF + NH)                // even -> u64 area 8B-aligned
// u64s (at ws + WS_FLOATS):
#define XPACK_OFF  ((size_t)0)                 // 2*NH (double-buffered packed x)
#define ZPACK_OFF  ((size_t)2 * NH)            // NH   (packed z / final x for CG)
#define PQSLOT_OFF ((size_t)3 * NH)            // 64   ((p,q) partials)
#define RZSLOT_OFF ((size_t)3 * NH + 64)       // 64   ((r,z) partials)
#define U64_TOTAL  ((size_t)3 * NH + 128)

__device__ __forceinline__ u64 pack_ev(int epoch, float v) {
    return ((u64)(unsigned)epoch << 32) | (u64)__float_as_uint(v);
}
__device__ __forceinline__ int   ep_of(u64 p)  { return (int)(p >> 32); }
__device__ __forceinline__ float val_of(u64 p) { return __uint_as_float((unsigned)p); }
__device__ __forceinline__ u64 pack2f(float lo, float hi) {
    return ((u64)__float_as_uint(hi) << 32) | (u64)__float_as_uint(lo);
}
__device__ __forceinline__ float lo_of(u64 p) { return __uint_as_float((unsigned)p); }
__device__ __forceinline__ float hi_of(u64 p) { return __uint_as_float((unsigned)(p >> 32)); }

__device__ __forceinline__ u64 aload(const u64* p) {
    return __hip_atomic_load(p, __ATOMIC_RELAXED, __HIP_MEMORY_SCOPE_AGENT);
}
__device__ __forceinline__ void astore(u64* p, u64 v) {
    __hip_atomic_store(p, v, __ATOMIC_RELAXED, __HIP_MEMORY_SCOPE_AGENT);
}

// ===== drive = u @ W_in.T  (+ init of u64 sync area, folded into block 0) =====
__global__ __launch_bounds__(256) void drive_kernel(
    const float* __restrict__ u, const float* __restrict__ Win,
    float* __restrict__ drive, float* __restrict__ ws)
{
    __shared__ float Wt[256 * 64];
    const int tid = threadIdx.x;
    if (blockIdx.x == 0) {           // init fold: zero packed-epoch area
        u64* ub = (u64*)(ws + WS_FLOATS);
        for (size_t i = tid; i < U64_TOTAL; i += 256) ub[i] = 0ull;
    }
    const int ic = blockIdx.x & 7;
    const int tc = blockIdx.x >> 3;
    const int i0 = ic * 256;
    for (int idx = tid; idx < 256 * 64; idx += 256) {
        int il = idx >> 6, k = idx & 63;
        Wt[k * 256 + il] = Win[(size_t)i0 * 64 + idx];
    }
    __syncthreads();
    for (int tt_ = 0; tt_ < 128; ++tt_) {
        int t = tc * 128 + tt_;
        const float* ur = u + (size_t)t * DIN;
        float acc = 0.f;
        #pragma unroll
        for (int k = 0; k < 64; ++k)
            acc = fmaf(Wt[k * 256 + tid], ur[k], acc);
        drive[(size_t)t * NH + i0 + tid] = acc;
    }
}

// ===== fused scan + gram + bvec: 256 blocks x 1024 threads =====
// Scan (blocks 0..63): R10-verbatim structure (single-buffered xls, trailing
// barrier — the barrier aligns wave probe timing; removing it cost +1.6 ms in
// R11). bvec accumulated by lane 0 AFTER the publish stores (off critical
// path) and written at the end. Workers (64..255): R8 verbatim.
__global__ __launch_bounds__(1024, 1) void scan_gram_kernel(
    const float* __restrict__ W, const float* __restrict__ drive,
    const float* __restrict__ y,
    float* __restrict__ X, u64* xpack, float* __restrict__ A,
    float* __restrict__ bv)
{
    __shared__ float xls[NH];          // 8 KB (scan)
    __shared__ float As[16][64];       // 4 KB (worker)
    __shared__ float Bs[16][64];       // 4 KB (worker)
    const int tid = threadIdx.x;

    if (blockIdx.x < 64) {
        // ================= scan path =====================================
        const int wave = tid >> 6;       // 16 waves
        const int lane = tid & 63;
        const int rowA = blockIdx.x * 32 + wave * 2;

        float4 wA[8], wB[8];
        {
            const float* wpA = W + (size_t)rowA * NH + lane * 4;
            const float* wpB = wpA + NH;
            #pragma unroll
            for (int j = 0; j < 8; ++j) {
                wA[j] = *(const float4*)(wpA + 256 * j);
                wB[j] = *(const float4*)(wpB + 256 * j);
            }
        }

        float b0 = 0.f, b1 = 0.f;        // bvec accumulators (lane 0)

        for (int t = 0; t < TT; ++t) {
            float2 dv = {0.f, 0.f};
            if (lane == 0) dv = *(const float2*)&drive[(size_t)t * NH + rowA];

            if (t == 0) {
                xls[tid] = 0.f; xls[tid + 1024] = 0.f;
            } else {
                const u64* src = xpack + (size_t)((t - 1) & 1) * NH;
                const int want = t;
                u64 a = aload(&src[tid]);
                u64 b = aload(&src[tid + 1024]);
                bool pa = true, pb = true;
                if (ep_of(a) >= want) { xls[tid] = val_of(a); pa = false; }
                if (ep_of(b) >= want) { xls[tid + 1024] = val_of(b); pb = false; }
                while (pa || pb) {
                    __builtin_amdgcn_s_sleep(1);
                    if (pa) { u64 v = aload(&src[tid]);
                              if (ep_of(v) >= want) { xls[tid] = val_of(v); pa = false; } }
                    if (pb) { u64 v = aload(&src[tid + 1024]);
                              if (ep_of(v) >= want) { xls[tid + 1024] = val_of(v); pb = false; } }
                }
            }
            __syncthreads();

            float a0 = 0.f, a1 = 0.f;
            #pragma unroll
            for (int j = 0; j < 8; ++j) {
                float4 xv = *(const float4*)&xls[lane * 4 + 256 * j];
                float4 va = wA[j], vb = wB[j];
                a0 = fmaf(va.x, xv.x, fmaf(va.y, xv.y, fmaf(va.z, xv.z, fmaf(va.w, xv.w, a0))));
                a1 = fmaf(vb.x, xv.x, fmaf(vb.y, xv.y, fmaf(vb.z, xv.z, fmaf(vb.w, xv.w, a1))));
            }
            #pragma unroll
            for (int m = 32; m; m >>= 1) { a0 += __shfl_xor(a0, m); a1 += __shfl_xor(a1, m); }

            if (lane == 0) {
                float v0 = tanhf(a0 + dv.x);
                float v1 = tanhf(a1 + dv.y);
                astore((u64*)&X[(size_t)t * NH + rowA], pack2f(v0, v1));
                u64* dst = xpack + (size_t)(t & 1) * NH;
                astore(&dst[rowA],     pack_ev(t + 1, v0));
                astore(&dst[rowA + 1], pack_ev(t + 1, v1));
                if (t >= WASH) {      // bvec fold: after publishes, off critical path
                    float yv = y[t];
                    b0 = fmaf(v0, yv, b0);
                    b1 = fmaf(v1, yv, b1);
                }
            }
            __syncthreads();   // xls stable until all reads done (probe aligner)
        }
        // final: make X[TT-1] provably visible, then sentinel epoch
        __threadfence();
        if (lane == 0) {
            u64* dst = xpack + (size_t)(TT & 1) * NH;   // buffer 0
            astore(&dst[rowA],     pack_ev(TT + 1, 0.f));
            astore(&dst[rowA + 1], pack_ev(TT + 1, 0.f));
            bv[rowA]     = b0;       // read by cg_kernel (stream-ordered)
            bv[rowA + 1] = b1;
        }
    } else {
        // ================= gram worker path (R8 verbatim) ==================
        const int wid = blockIdx.x - 64;         // 0..191
        int ti0[3], tj0[3]; int nt = 0;
        for (int L = wid; L < NTILE; L += NWORK) {
            int rem = L, a = 0;
            while (rem >= 32 - a) { rem -= 32 - a; ++a; }
            ti0[nt] = a * 64; tj0[nt] = (a + rem) * 64; ++nt;
        }
        float4 acc4[3] = {};
        const int ty = tid >> 5, tx = tid & 31;
        const u64* Xp = (const u64*)X;

        const int nch = (TW + 15) / 16;          // 244
        for (int ch = 0; ch < nch; ++ch) {
            const int tb = WASH + ch * 16;
            const int te = (tb + 15 < TT) ? tb + 15 : TT - 1;
            const int want = te + 2;
            const u64* buf = xpack + (size_t)((te + 1) & 1) * NH;
            if (tid < nt * 128) {
                int tt_ = tid >> 7, local = tid & 127;
                int base = (local & 64) ? tj0[tt_] : ti0[tt_];
                int r = base + (local & 63);
                u64 v = aload(&buf[r]);
                while (ep_of(v) < want) { __builtin_amdgcn_s_sleep(64); v = aload(&buf[r]); }
            }
            __syncthreads();

            for (int tt_ = 0; tt_ < nt; ++tt_) {
                const int i0 = ti0[tt_], j0 = tj0[tt_];
                {   // stage 16x64 A-cols and B-cols (u64 = 2 floats per thread)
                    int v = tid & 511;
                    int kk = v >> 5, c2 = v & 31;
                    int t = tb + kk;
                    int base = (tid < 512) ? i0 : j0;
                    float lo = 0.f, hi = 0.f;
                    if (t < TT) {
                        u64 w_ = aload(&Xp[((size_t)t * NH + base) / 2 + c2]);
                        lo = lo_of(w_); hi = hi_of(w_);
                    }
                    float* Sh = (tid < 512) ? &As[kk][c2 * 2] : &Bs[kk][c2 * 2];
                    Sh[0] = lo; Sh[1] = hi;
                }
                __syncthreads();
                float4 a = acc4[tt_];
                #pragma unroll
                for (int k = 0; k < 16; ++k) {
                    float2 av = *(const float2*)&As[k][ty * 2];
                    float2 bv2 = *(const float2*)&Bs[k][tx * 2];
                    a.x = fmaf(av.x, bv2.x, a.x); a.y = fmaf(av.x, bv2.y, a.y);
                    a.z = fmaf(av.y, bv2.x, a.z); a.w = fmaf(av.y, bv2.y, a.w);
                }
                acc4[tt_] = a;
                __syncthreads();
            }
        }
        // writeout (scan fully done: last chunk required the sentinels)
        for (int tt_ = 0; tt_ < nt; ++tt_) {
            const int i0 = ti0[tt_], j0 = tj0[tt_];
            const bool diag = (i0 == j0);
            float4 a = acc4[tt_];
            float vals[2][2] = {{a.x, a.y}, {a.z, a.w}};
            #pragma unroll
            for (int aa = 0; aa < 2; ++aa) {
                int gi = i0 + ty * 2 + aa;
                #pragma unroll
                for (int bb = 0; bb < 2; ++bb) {
                    int gj = j0 + tx * 2 + bb;
                    float v = vals[aa][bb];
                    if (gi == gj) v += LAMBDA;
                    A[(size_t)gi * NH + gj] = v;
                    if (!diag) A[(size_t)gj * NH + gi] = v;
                }
            }
        }
    }
}

// ===== truth-based Jacobi-PCG (R10 verbatim, proven) + out epilogue =====
__global__ __launch_bounds__(1024, 1) void cg_kernel(
    const float* __restrict__ A, const float* __restrict__ bvec,
    const float* __restrict__ X, float* __restrict__ out,
    u64* zpack, u64* pqslot, u64* rzslot)
{
    __shared__ float pls[NH];        // persistent p (8 KB)
    __shared__ float zls[NH];        // gathered z / final Wout (8 KB)
    __shared__ float r32[32], x32[32], q32[32], inv32[32];
    __shared__ float csh[2];
    const int tid     = threadIdx.x;
    const int r_local = tid >> 5;
    const int lane32  = tid & 31;
    const int row0 = blockIdx.x * 32;
    const int row  = row0 + r_local;

    float4 areg[16];                 // A[row][lane32*4 + 128j ..] resident
    {
        const float* ap = A + (size_t)row * NH + lane32 * 4;
        #pragma unroll
        for (int j = 0; j < 16; ++j) areg[j] = *(const float4*)(ap + 128 * j);
    }

    pls[tid] = 0.f; pls[tid + 1024] = 0.f;

    if (tid < 32) {
        int i = row0 + tid;
        float bi = bvec[i];
        float iv = 1.0f / A[(size_t)i * NH + i];   // invdiag folded in
        inv32[tid] = iv;
        x32[tid] = 0.f; r32[tid] = bi;
        float zi = iv * bi;
        astore(&zpack[i], pack_ev(1, zi));
        float part = bi * zi;
        #pragma unroll
        for (int m = 16; m; m >>= 1) part += __shfl_xor(part, m, 32);
        if (tid == 0) astore(&rzslot[blockIdx.x], pack_ev(1, part));
    }
    __syncthreads();

    float rho_prev = 1.f;

    for (int it = 0; it < CG_ITERS; ++it) {
        // --- phase 1: gather z (epoch it+1) + rz slots -> rho, beta ---
        {
            const int want = it + 1;
            u64 a = aload(&zpack[tid]);
            u64 b = aload(&zpack[tid + 1024]);
            bool pa = true, pb = true;
            if (ep_of(a) >= want) { zls[tid] = val_of(a); pa = false; }
            if (ep_of(b) >= want) { zls[tid + 1024] = val_of(b); pb = false; }
            while (pa || pb) {
                __builtin_amdgcn_s_sleep(1);
                if (pa) { u64 v = aload(&zpack[tid]);
                          if (ep_of(v) >= want) { zls[tid] = val_of(v); pa = false; } }
                if (pb) { u64 v = aload(&zpack[tid + 1024]);
                          if (ep_of(v) >= want) { zls[tid + 1024] = val_of(v); pb = false; } }
            }
        }
        if (tid < 64) {
            u64 v = aload(&rzslot[tid]);
            while (ep_of(v) < it + 1) { __builtin_amdgcn_s_sleep(1); v = aload(&rzslot[tid]); }
            float s = val_of(v);
            #pragma unroll
            for (int m = 32; m; m >>= 1) s += __shfl_xor(s, m);
            if (tid == 0) csh[1] = s;
        }
        __syncthreads();
        float rho = csh[1];
        float beta = (it == 0) ? 0.f : ((rho_prev != 0.f) ? rho / rho_prev : 0.f);

        pls[tid]        = fmaf(beta, pls[tid],        zls[tid]);
        pls[tid + 1024] = fmaf(beta, pls[tid + 1024], zls[tid + 1024]);
        __syncthreads();

        float acc = 0.f;
        #pragma unroll
        for (int j = 0; j < 16; ++j) {
            float4 pv = *(const float4*)&pls[lane32 * 4 + 128 * j];
            float4 av = areg[j];
            acc = fmaf(av.x, pv.x, fmaf(av.y, pv.y,
                  fmaf(av.z, pv.z, fmaf(av.w, pv.w, acc))));
        }
        #pragma unroll
        for (int m = 16; m; m >>= 1) acc += __shfl_xor(acc, m, 32);
        if (lane32 == 0) q32[r_local] = acc;
        __syncthreads();

        if (tid < 32) {
            float t1 = q32[tid] * pls[row0 + tid];
            #pragma unroll
            for (int m = 16; m; m >>= 1) t1 += __shfl_xor(t1, m, 32);
            if (tid == 0) astore(&pqslot[blockIdx.x], pack_ev(it + 1, t1));
        }
        if (tid < 64) {
            u64 v = aload(&pqslot[tid]);
            while (ep_of(v) < it + 1) { __builtin_amdgcn_s_sleep(1); v = aload(&pqslot[tid]); }
            float s = val_of(v);
            #pragma unroll
            for (int m = 32; m; m >>= 1) s += __shfl_xor(s, m);
            if (tid == 0) csh[0] = s;
        }
        __syncthreads();
        float pq = csh[0];
        float alpha = (pq != 0.f) ? rho / pq : 0.f;

        if (tid < 32) {
            int i = row0 + tid;
            float pi = pls[i], qi = q32[tid];
            x32[tid] = fmaf(alpha, pi, x32[tid]);
            float ri = r32[tid] - alpha * qi;
            r32[tid] = ri;
            float zi = inv32[tid] * ri;
            astore(&zpack[i], pack_ev(it + 2, zi));
            float t2 = ri * zi;
            #pragma unroll
            for (int m = 16; m; m >>= 1) t2 += __shfl_xor(t2, m, 32);
            if (tid == 0) astore(&rzslot[blockIdx.x], pack_ev(it + 2, t2));
        }
        rho_prev = rho;
        __syncthreads();
    }

    // ===== out epilogue: publish final x (epoch CG_ITERS+2), gather, project =====
    if (tid < 32) {
        int i = row0 + tid;
        astore(&zpack[i], pack_ev(CG_ITERS + 2, x32[tid]));
    }
    {
        const int want = CG_ITERS + 2;
        u64 a = aload(&zpack[tid]);
        u64 b = aload(&zpack[tid + 1024]);
        bool pa = true, pb = true;
        if (ep_of(a) >= want) { zls[tid] = val_of(a); pa = false; }
        if (ep_of(b) >= want) { zls[tid + 1024] = val_of(b); pb = false; }
        while (pa || pb) {
            __builtin_amdgcn_s_sleep(1);
            if (pa) { u64 v = aload(&zpack[tid]);
                      if (ep_of(v) >= want) { zls[tid] = val_of(v); pa = false; } }
            if (pb) { u64 v = aload(&zpack[tid + 1024]);
                      if (ep_of(v) >= want) { zls[tid + 1024] = val_of(v); pb = false; } }
        }
    }
    __syncthreads();
    {
        const int i0r = (TW * (int)blockIdx.x) >> 6;       // TW*b/64
        const int i1r = (TW * ((int)blockIdx.x + 1)) >> 6;
        const int wave = tid >> 6, lane = tid & 63;
        for (int i = i0r + wave; i < i1r; i += 16) {
            const float* xr = X + (size_t)(WASH + i) * NH;
            float acc = 0.f;
            #pragma unroll
            for (int j = 0; j < 32; ++j)
                acc = fmaf(xr[j * 64 + lane], zls[j * 64 + lane], acc);
            #pragma unroll
            for (int m = 32; m; m >>= 1) acc += __shfl_xor(acc, m);
            if (lane == 0) out[i] = acc;
        }
    }
}

extern "C" void kernel_launch(void* const* d_in, const int* in_sizes, int n_in,
                              void* d_out, int out_size, void* d_ws, size_t ws_size,
                              hipStream_t stream)
{
    const float* u    = (const float*)d_in[0];   // (4096, 64)
    const float* y    = (const float*)d_in[1];   // (4096, 1)
    const float* Win  = (const float*)d_in[2];   // (2048, 64)
    const float* Wres = (const float*)d_in[3];   // (2048, 2048)
    // d_in[4] = washout (==200), hardcoded as WASH

    float* ws = (float*)d_ws;
    float* X     = ws + X_OFF;
    float* drive = ws + DRIVE_OFF;
    float* A     = ws + A_OFF;
    u64*   ub    = (u64*)(ws + WS_FLOATS);
    u64*   xpack  = ub + XPACK_OFF;
    u64*   zpack  = ub + ZPACK_OFF;
    u64*   pqslot = ub + PQSLOT_OFF;
    u64*   rzslot = ub + RZSLOT_OFF;

    drive_kernel<<<256, 256, 0, stream>>>(u, Win, drive, ws);
    scan_gram_kernel<<<256, 1024, 0, stream>>>(Wres, drive, y, X, xpack, A,
                                               ws + B_OFF);
    cg_kernel<<<CG_BLOCKS, 1024, 0, stream>>>(A, ws + B_OFF, X, (float*)d_out,
                                              zpack, pqslot, rzslot);
}

// Round 13
// 11743.391 us; speedup vs baseline: 1.2458x; 1.0285x over previous
//
#include <hip/hip_runtime.h>
#include <math.h>

// ===== problem constants (washout hardcoded=200 per reference) =====
#define NH      2048
#define TT      4096
#define DIN     64
#define WASH    200
#define TW      (TT - WASH)      // 3896
#define LAMBDA  1e-6f

#define CG_BLOCKS    64
#define CG_ITERS     192
#define NTILE        528         // 32*33/2 upper-tri 64x64 tiles
#define NWORK        192         // gram worker blocks (64..255)

typedef unsigned long long u64;

// ===== workspace layout =====
// floats:
#define X_OFF      ((size_t)0)                 // TT*NH (32 MB)
#define DRIVE_OFF  ((size_t)TT * NH)           // TT*NH (dead after scan)
#define A_OFF      DRIVE_OFF                   // NH*NH aliases drive rows<2048
#define B_OFF      ((size_t)2 * TT * NH)       // NH
#define WS_FLOATS  (B_OFF + NH)                // even -> u64 area 8B-aligned
// u64s (at ws + WS_FLOATS):
#define XPACK_OFF  ((size_t)0)                 // 2*NH (double-buffered packed x)
#define ZPACK_OFF  ((size_t)2 * NH)            // NH   (packed z / final x for CG)
#define PQSLOT_OFF ((size_t)3 * NH)            // 64   ((p,q) partials)
#define RZSLOT_OFF ((size_t)3 * NH + 64)       // 64   ((r,z) partials)
#define U64_TOTAL  ((size_t)3 * NH + 128)

__device__ __forceinline__ u64 pack_ev(int epoch, float v) {
    return ((u64)(unsigned)epoch << 32) | (u64)__float_as_uint(v);
}
__device__ __forceinline__ int   ep_of(u64 p)  { return (int)(p >> 32); }
__device__ __forceinline__ float val_of(u64 p) { return __uint_as_float((unsigned)p); }
__device__ __forceinline__ u64 pack2f(float lo, float hi) {
    return ((u64)__float_as_uint(hi) << 32) | (u64)__float_as_uint(lo);
}
__device__ __forceinline__ float lo_of(u64 p) { return __uint_as_float((unsigned)p); }
__device__ __forceinline__ float hi_of(u64 p) { return __uint_as_float((unsigned)(p >> 32)); }

__device__ __forceinline__ u64 aload(const u64* p) {
    return __hip_atomic_load(p, __ATOMIC_RELAXED, __HIP_MEMORY_SCOPE_AGENT);
}
__device__ __forceinline__ void astore(u64* p, u64 v) {
    __hip_atomic_store(p, v, __ATOMIC_RELAXED, __HIP_MEMORY_SCOPE_AGENT);
}

// ===== drive = u @ W_in.T  (+ init of u64 sync area, folded into block 0) =====
__global__ __launch_bounds__(256) void drive_kernel(
    const float* __restrict__ u, const float* __restrict__ Win,
    float* __restrict__ drive, float* __restrict__ ws)
{
    __shared__ float Wt[256 * 64];
    const int tid = threadIdx.x;
    if (blockIdx.x == 0) {           // init fold: zero packed-epoch area
        u64* ub = (u64*)(ws + WS_FLOATS);
        for (size_t i = tid; i < U64_TOTAL; i += 256) ub[i] = 0ull;
    }
    const int ic = blockIdx.x & 7;
    const int tc = blockIdx.x >> 3;
    const int i0 = ic * 256;
    for (int idx = tid; idx < 256 * 64; idx += 256) {
        int il = idx >> 6, k = idx & 63;
        Wt[k * 256 + il] = Win[(size_t)i0 * 64 + idx];
    }
    __syncthreads();
    for (int tt_ = 0; tt_ < 128; ++tt_) {
        int t = tc * 128 + tt_;
        const float* ur = u + (size_t)t * DIN;
        float acc = 0.f;
        #pragma unroll
        for (int k = 0; k < 64; ++k)
            acc = fmaf(Wt[k * 256 + tid], ur[k], acc);
        drive[(size_t)t * NH + i0 + tid] = acc;
    }
}

// ===== fused scan + gram + bvec: 256 blocks x 1024 threads (R12 verbatim) =====
// Scan (blocks 0..63): single-buffered xls + trailing barrier (probe aligner —
// removing it cost +1.6 ms in R11). bvec accumulated by lane 0 after the
// publish stores. Workers (64..255): R8-proven consumer path.
__global__ __launch_bounds__(1024, 1) void scan_gram_kernel(
    const float* __restrict__ W, const float* __restrict__ drive,
    const float* __restrict__ y,
    float* __restrict__ X, u64* xpack, float* __restrict__ A,
    float* __restrict__ bv)
{
    __shared__ float xls[NH];          // 8 KB (scan)
    __shared__ float As[16][64];       // 4 KB (worker)
    __shared__ float Bs[16][64];       // 4 KB (worker)
    const int tid = threadIdx.x;

    if (blockIdx.x < 64) {
        // ================= scan path =====================================
        const int wave = tid >> 6;       // 16 waves
        const int lane = tid & 63;
        const int rowA = blockIdx.x * 32 + wave * 2;

        float4 wA[8], wB[8];
        {
            const float* wpA = W + (size_t)rowA * NH + lane * 4;
            const float* wpB = wpA + NH;
            #pragma unroll
            for (int j = 0; j < 8; ++j) {
                wA[j] = *(const float4*)(wpA + 256 * j);
                wB[j] = *(const float4*)(wpB + 256 * j);
            }
        }

        float b0 = 0.f, b1 = 0.f;        // bvec accumulators (lane 0)

        for (int t = 0; t < TT; ++t) {
            float2 dv = {0.f, 0.f};
            if (lane == 0) dv = *(const float2*)&drive[(size_t)t * NH + rowA];

            if (t == 0) {
                xls[tid] = 0.f; xls[tid + 1024] = 0.f;
            } else {
                const u64* src = xpack + (size_t)((t - 1) & 1) * NH;
                const int want = t;
                u64 a = aload(&src[tid]);
                u64 b = aload(&src[tid + 1024]);
                bool pa = true, pb = true;
                if (ep_of(a) >= want) { xls[tid] = val_of(a); pa = false; }
                if (ep_of(b) >= want) { xls[tid + 1024] = val_of(b); pb = false; }
                while (pa || pb) {
                    __builtin_amdgcn_s_sleep(1);
                    if (pa) { u64 v = aload(&src[tid]);
                              if (ep_of(v) >= want) { xls[tid] = val_of(v); pa = false; } }
                    if (pb) { u64 v = aload(&src[tid + 1024]);
                              if (ep_of(v) >= want) { xls[tid + 1024] = val_of(v); pb = false; } }
                }
            }
            __syncthreads();

            float a0 = 0.f, a1 = 0.f;
            #pragma unroll
            for (int j = 0; j < 8; ++j) {
                float4 xv = *(const float4*)&xls[lane * 4 + 256 * j];
                float4 va = wA[j], vb = wB[j];
                a0 = fmaf(va.x, xv.x, fmaf(va.y, xv.y, fmaf(va.z, xv.z, fmaf(va.w, xv.w, a0))));
                a1 = fmaf(vb.x, xv.x, fmaf(vb.y, xv.y, fmaf(vb.z, xv.z, fmaf(vb.w, xv.w, a1))));
            }
            #pragma unroll
            for (int m = 32; m; m >>= 1) { a0 += __shfl_xor(a0, m); a1 += __shfl_xor(a1, m); }

            if (lane == 0) {
                float v0 = tanhf(a0 + dv.x);
                float v1 = tanhf(a1 + dv.y);
                astore((u64*)&X[(size_t)t * NH + rowA], pack2f(v0, v1));
                u64* dst = xpack + (size_t)(t & 1) * NH;
                astore(&dst[rowA],     pack_ev(t + 1, v0));
                astore(&dst[rowA + 1], pack_ev(t + 1, v1));
                if (t >= WASH) {      // bvec fold: after publishes, off critical path
                    float yv = y[t];
                    b0 = fmaf(v0, yv, b0);
                    b1 = fmaf(v1, yv, b1);
                }
            }
            __syncthreads();   // xls stable until all reads done (probe aligner)
        }
        // final: make X[TT-1] provably visible, then sentinel epoch
        __threadfence();
        if (lane == 0) {
            u64* dst = xpack + (size_t)(TT & 1) * NH;   // buffer 0
            astore(&dst[rowA],     pack_ev(TT + 1, 0.f));
            astore(&dst[rowA + 1], pack_ev(TT + 1, 0.f));
            bv[rowA]     = b0;       // read by cg_kernel (stream-ordered)
            bv[rowA + 1] = b1;
        }
    } else {
        // ================= gram worker path (R8 verbatim) ==================
        const int wid = blockIdx.x - 64;         // 0..191
        int ti0[3], tj0[3]; int nt = 0;
        for (int L = wid; L < NTILE; L += NWORK) {
            int rem = L, a = 0;
            while (rem >= 32 - a) { rem -= 32 - a; ++a; }
            ti0[nt] = a * 64; tj0[nt] = (a + rem) * 64; ++nt;
        }
        float4 acc4[3] = {};
        const int ty = tid >> 5, tx = tid & 31;
        const u64* Xp = (const u64*)X;

        const int nch = (TW + 15) / 16;          // 244
        for (int ch = 0; ch < nch; ++ch) {
            const int tb = WASH + ch * 16;
            const int te = (tb + 15 < TT) ? tb + 15 : TT - 1;
            const int want = te + 2;
            const u64* buf = xpack + (size_t)((te + 1) & 1) * NH;
            if (tid < nt * 128) {
                int tt_ = tid >> 7, local = tid & 127;
                int base = (local & 64) ? tj0[tt_] : ti0[tt_];
                int r = base + (local & 63);
                u64 v = aload(&buf[r]);
                while (ep_of(v) < want) { __builtin_amdgcn_s_sleep(64); v = aload(&buf[r]); }
            }
            __syncthreads();

            for (int tt_ = 0; tt_ < nt; ++tt_) {
                const int i0 = ti0[tt_], j0 = tj0[tt_];
                {   // stage 16x64 A-cols and B-cols (u64 = 2 floats per thread)
                    int v = tid & 511;
                    int kk = v >> 5, c2 = v & 31;
                    int t = tb + kk;
                    int base = (tid < 512) ? i0 : j0;
                    float lo = 0.f, hi = 0.f;
                    if (t < TT) {
                        u64 w_ = aload(&Xp[((size_t)t * NH + base) / 2 + c2]);
                        lo = lo_of(w_); hi = hi_of(w_);
                    }
                    float* Sh = (tid < 512) ? &As[kk][c2 * 2] : &Bs[kk][c2 * 2];
                    Sh[0] = lo; Sh[1] = hi;
                }
                __syncthreads();
                float4 a = acc4[tt_];
                #pragma unroll
                for (int k = 0; k < 16; ++k) {
                    float2 av = *(const float2*)&As[k][ty * 2];
                    float2 bv2 = *(const float2*)&Bs[k][tx * 2];
                    a.x = fmaf(av.x, bv2.x, a.x); a.y = fmaf(av.x, bv2.y, a.y);
                    a.z = fmaf(av.y, bv2.x, a.z); a.w = fmaf(av.y, bv2.y, a.w);
                }
                acc4[tt_] = a;
                __syncthreads();
            }
        }
        // writeout (scan fully done: last chunk required the sentinels)
        for (int tt_ = 0; tt_ < nt; ++tt_) {
            const int i0 = ti0[tt_], j0 = tj0[tt_];
            const bool diag = (i0 == j0);
            float4 a = acc4[tt_];
            float vals[2][2] = {{a.x, a.y}, {a.z, a.w}};
            #pragma unroll
            for (int aa = 0; aa < 2; ++aa) {
                int gi = i0 + ty * 2 + aa;
                #pragma unroll
                for (int bb = 0; bb < 2; ++bb) {
                    int gj = j0 + tx * 2 + bb;
                    float v = vals[aa][bb];
                    if (gi == gj) v += LAMBDA;
                    A[(size_t)gi * NH + gj] = v;
                    if (!diag) A[(size_t)gj * NH + gi] = v;
                }
            }
        }
    }
}

// ===== truth-based Jacobi-PCG (proven structure) + out epilogue, 192 iters =====
__global__ __launch_bounds__(1024, 1) void cg_kernel(
    const float* __restrict__ A, const float* __restrict__ bvec,
    const float* __restrict__ X, float* __restrict__ out,
    u64* zpack, u64* pqslot, u64* rzslot)
{
    __shared__ float pls[NH];        // persistent p (8 KB)
    __shared__ float zls[NH];        // gathered z / final Wout (8 KB)
    __shared__ float r32[32], x32[32], q32[32], inv32[32];
    __shared__ float csh[2];
    const int tid     = threadIdx.x;
    const int r_local = tid >> 5;
    const int lane32  = tid & 31;
    const int row0 = blockIdx.x * 32;
    const int row  = row0 + r_local;

    float4 areg[16];                 // A[row][lane32*4 + 128j ..] resident
    {
        const float* ap = A + (size_t)row * NH + lane32 * 4;
        #pragma unroll
        for (int j = 0; j < 16; ++j) areg[j] = *(const float4*)(ap + 128 * j);
    }

    pls[tid] = 0.f; pls[tid + 1024] = 0.f;

    if (tid < 32) {
        int i = row0 + tid;
        float bi = bvec[i];
        float iv = 1.0f / A[(size_t)i * NH + i];   // invdiag folded in
        inv32[tid] = iv;
        x32[tid] = 0.f; r32[tid] = bi;
        float zi = iv * bi;
        astore(&zpack[i], pack_ev(1, zi));
        float part = bi * zi;
        #pragma unroll
        for (int m = 16; m; m >>= 1) part += __shfl_xor(part, m, 32);
        if (tid == 0) astore(&rzslot[blockIdx.x], pack_ev(1, part));
    }
    __syncthreads();

    float rho_prev = 1.f;

    for (int it = 0; it < CG_ITERS; ++it) {
        // --- phase 1: gather z (epoch it+1) + rz slots -> rho, beta ---
        {
            const int want = it + 1;
            u64 a = aload(&zpack[tid]);
            u64 b = aload(&zpack[tid + 1024]);
            bool pa = true, pb = true;
            if (ep_of(a) >= want) { zls[tid] = val_of(a); pa = false; }
            if (ep_of(b) >= want) { zls[tid + 1024] = val_of(b); pb = false; }
            while (pa || pb) {
                __builtin_amdgcn_s_sleep(1);
                if (pa) { u64 v = aload(&zpack[tid]);
                          if (ep_of(v) >= want) { zls[tid] = val_of(v); pa = false; } }
                if (pb) { u64 v = aload(&zpack[tid + 1024]);
                          if (ep_of(v) >= want) { zls[tid + 1024] = val_of(v); pb = false; } }
            }
        }
        if (tid < 64) {
            u64 v = aload(&rzslot[tid]);
            while (ep_of(v) < it + 1) { __builtin_amdgcn_s_sleep(1); v = aload(&rzslot[tid]); }
            float s = val_of(v);
            #pragma unroll
            for (int m = 32; m; m >>= 1) s += __shfl_xor(s, m);
            if (tid == 0) csh[1] = s;
        }
        __syncthreads();
        float rho = csh[1];
        float beta = (it == 0) ? 0.f : ((rho_prev != 0.f) ? rho / rho_prev : 0.f);

        pls[tid]        = fmaf(beta, pls[tid],        zls[tid]);
        pls[tid + 1024] = fmaf(beta, pls[tid + 1024], zls[tid + 1024]);
        __syncthreads();

        float acc = 0.f;
        #pragma unroll
        for (int j = 0; j < 16; ++j) {
            float4 pv = *(const float4*)&pls[lane32 * 4 + 128 * j];
            float4 av = areg[j];
            acc = fmaf(av.x, pv.x, fmaf(av.y, pv.y,
                  fmaf(av.z, pv.z, fmaf(av.w, pv.w, acc))));
        }
        #pragma unroll
        for (int m = 16; m; m >>= 1) acc += __shfl_xor(acc, m, 32);
        if (lane32 == 0) q32[r_local] = acc;
        __syncthreads();

        if (tid < 32) {
            float t1 = q32[tid] * pls[row0 + tid];
            #pragma unroll
            for (int m = 16; m; m >>= 1) t1 += __shfl_xor(t1, m, 32);
            if (tid == 0) astore(&pqslot[blockIdx.x], pack_ev(it + 1, t1));
        }
        if (tid < 64) {
            u64 v = aload(&pqslot[tid]);
            while (ep_of(v) < it + 1) { __builtin_amdgcn_s_sleep(1); v = aload(&pqslot[tid]); }
            float s = val_of(v);
            #pragma unroll
            for (int m = 32; m; m >>= 1) s += __shfl_xor(s, m);
            if (tid == 0) csh[0] = s;
        }
        __syncthreads();
        float pq = csh[0];
        float alpha = (pq != 0.f) ? rho / pq : 0.f;

        if (tid < 32) {
            int i = row0 + tid;
            float pi = pls[i], qi = q32[tid];
            x32[tid] = fmaf(alpha, pi, x32[tid]);
            float ri = r32[tid] - alpha * qi;
            r32[tid] = ri;
            float zi = inv32[tid] * ri;
            astore(&zpack[i], pack_ev(it + 2, zi));
            float t2 = ri * zi;
            #pragma unroll
            for (int m = 16; m; m >>= 1) t2 += __shfl_xor(t2, m, 32);
            if (tid == 0) astore(&rzslot[blockIdx.x], pack_ev(it + 2, t2));
        }
        rho_prev = rho;
        __syncthreads();
    }

    // ===== out epilogue: publish final x (epoch CG_ITERS+2), gather, project =====
    if (tid < 32) {
        int i = row0 + tid;
        astore(&zpack[i], pack_ev(CG_ITERS + 2, x32[tid]));
    }
    {
        const int want = CG_ITERS + 2;
        u64 a = aload(&zpack[tid]);
        u64 b = aload(&zpack[tid + 1024]);
        bool pa = true, pb = true;
        if (ep_of(a) >= want) { zls[tid] = val_of(a); pa = false; }
        if (ep_of(b) >= want) { zls[tid + 1024] = val_of(b); pb = false; }
        while (pa || pb) {
            __builtin_amdgcn_s_sleep(1);
            if (pa) { u64 v = aload(&zpack[tid]);
                      if (ep_of(v) >= want) { zls[tid] = val_of(v); pa = false; } }
            if (pb) { u64 v = aload(&zpack[tid + 1024]);
                      if (ep_of(v) >= want) { zls[tid + 1024] = val_of(v); pb = false; } }
        }
    }
    __syncthreads();
    {
        const int i0r = (TW * (int)blockIdx.x) >> 6;       // TW*b/64
        const int i1r = (TW * ((int)blockIdx.x + 1)) >> 6;
        const int wave = tid >> 6, lane = tid & 63;
        for (int i = i0r + wave; i < i1r; i += 16) {
            const float* xr = X + (size_t)(WASH + i) * NH;
            float acc = 0.f;
            #pragma unroll
            for (int j = 0; j < 32; ++j)
                acc = fmaf(xr[j * 64 + lane], zls[j * 64 + lane], acc);
            #pragma unroll
            for (int m = 32; m; m >>= 1) acc += __shfl_xor(acc, m);
            if (lane == 0) out[i] = acc;
        }
    }
}

extern "C" void kernel_launch(void* const* d_in, const int* in_sizes, int n_in,
                              void* d_out, int out_size, void* d_ws, size_t ws_size,
                              hipStream_t stream)
{
    const float* u    = (const float*)d_in[0];   // (4096, 64)
    const float* y    = (const float*)d_in[1];   // (4096, 1)
    const float* Win  = (const float*)d_in[2];   // (2048, 64)
    const float* Wres = (const float*)d_in[3];   // (2048, 2048)
    // d_in[4] = washout (==200), hardcoded as WASH

    float* ws = (float*)d_ws;
    float* X     = ws + X_OFF;
    float* drive = ws + DRIVE_OFF;
    float* A     = ws + A_OFF;
    u64*   ub    = (u64*)(ws + WS_FLOATS);
    u64*   xpack  = ub + XPACK_OFF;
    u64*   zpack  = ub + ZPACK_OFF;
    u64*   pqslot = ub + PQSLOT_OFF;
    u64*   rzslot = ub + RZSLOT_OFF;

    drive_kernel<<<256, 256, 0, stream>>>(u, Win, drive, ws);
    scan_gram_kernel<<<256, 1024, 0, stream>>>(Wres, drive, y, X, xpack, A,
                                               ws + B_OFF);
    cg_kernel<<<CG_BLOCKS, 1024, 0, stream>>>(A, ws + B_OFF, X, (float*)d_out,
                                              zpack, pqslot, rzslot);
}